// Round 4
// baseline (242.133 us; speedup 1.0000x reference)
//
#include <hip/hip_runtime.h>
#include <hip/hip_bf16.h>
#include <stdint.h>

#define TKS    4096   // tokens = 2*2048
#define KD     4096   // in_features
#define NSF    410    // split_f
#define NPARTS 10
#define NPAD   512    // padded Wfc rows (8 row-blocks of 64)
#define OUTF   4096

#define BM 64
#define BN 64
#define BK 128        // two 64-wide granule tiles per K iteration

typedef unsigned short u16;
typedef __attribute__((ext_vector_type(8))) short bf16x8;
typedef __attribute__((ext_vector_type(4))) float f32x4;

// ---- workspace layout (~38.0 MB) ----
#define WS_XB  0                                     // u16[4096*4096] swizzled bf16 x
#define WS_BSW ((size_t)TKS * KD * 2)                // u16[512*4096] swizzled bf16 Wfc
#define WS_GP  (WS_BSW + (size_t)NPAD * KD * 2)      // float[4][512][12] G/c partials
#define WS_SX  (WS_GP + (size_t)4 * NPAD * 12 * 4)   // float[4096*10]

__device__ inline u16 f2bf(float f) {
    union { __hip_bfloat16 b; u16 u; } cv;
    cv.b = __float2bfloat16(f);
    return cv.u;
}

typedef __attribute__((address_space(3))) unsigned int as3_uint;
typedef __attribute__((address_space(1))) unsigned int as1_uint;
__device__ inline void gl_lds16(const void* g, void* l) {
    __builtin_amdgcn_global_load_lds((as1_uint*)(uintptr_t)g,
                                     (as3_uint*)(uintptr_t)l, 16, 0, 0);
}

// granule index g in [0,512) -> (row, col) of a 64x64 tile.
// g = slot*64 + q*16 + ml ; slot = hi*4 + ks*2 + lo
// row = hi*32 + lo*16 + ml ; col = ks*32 + q*8
// MFMA read for (hi,lo,ks): addr = (slot*64 + lane)*16B -> conflict-free (proven R2/R3).

// ============ fuse_x: x -> xb (bf16 granule-tiled) + sx (f32 full-K) =========
// 512 blocks x 8 tokens x full K. Reads x ONCE, coalesced (256B segments);
// granule writes cover full 128B lines per wave.
__global__ __launch_bounds__(256) void fuse_x(const float* __restrict__ x,
                                              const float* __restrict__ Wsel,
                                              const float* __restrict__ bsel,
                                              u16* __restrict__ xb,
                                              float* __restrict__ sx) {
    __shared__ float wsl[NPARTS][1024];   // 40 KB Wsel chunk
    __shared__ float sxp[8][NPARTS];

    const int tid = threadIdx.x;
    const int b   = blockIdx.x;
    const int c   = tid & 7;          // col granule within 64-col tile
    const int r   = (tid >> 3) & 7;   // token within block
    const int kq  = tid >> 6;         // kt phase 0..3

    const int tb = b >> 3, b7 = b & 7;
    const int hi = b7 >> 2, lo = (b7 >> 1) & 1, ml = (b7 & 1) * 8 + r;
    const int slot = hi * 4 + (c >> 2) * 2 + lo;
    const int g    = slot * 64 + (c & 3) * 16 + ml;

    if (tid < 8 * NPARTS) sxp[tid / NPARTS][tid % NPARTS] = 0.f;

    float acc[NPARTS];
#pragma unroll
    for (int n = 0; n < NPARTS; ++n) acc[n] = 0.f;

    const float* xrow = x + (size_t)(b * 8 + r) * KD;

    for (int st = 0; st < 4; ++st) {
        __syncthreads();
#pragma unroll
        for (int it = 0; it < 10; ++it) {
            int idx = it * 256 + tid;               // 0..2559 float4 slots
            int n = idx >> 8, c4 = (idx & 255) * 4;
            *(float4*)&wsl[n][c4] = *(const float4*)&Wsel[n * KD + st * 1024 + c4];
        }
        __syncthreads();
#pragma unroll
        for (int i2 = 0; i2 < 4; ++i2) {
            const int ktl = (st * 4 + i2) * 4 + kq;
            const int kg  = ktl * 64 + c * 8;
            float4 v0 = *(const float4*)&xrow[kg];
            float4 v1 = *(const float4*)&xrow[kg + 4];
            u16 h[8] = { f2bf(v0.x), f2bf(v0.y), f2bf(v0.z), f2bf(v0.w),
                         f2bf(v1.x), f2bf(v1.y), f2bf(v1.z), f2bf(v1.w) };
            *(uint4*)&xb[((size_t)(tb * 64 + ktl) * 512 + g) * 8] = *(uint4*)h;
            const int cloc = (i2 * 4 + kq) * 64 + c * 8;
#pragma unroll
            for (int n = 0; n < NPARTS; ++n) {
                float4 w0 = *(float4*)&wsl[n][cloc];
                float4 w1 = *(float4*)&wsl[n][cloc + 4];
                acc[n] += v0.x * w0.x + v0.y * w0.y + v0.z * w0.z + v0.w * w0.w
                        + v1.x * w1.x + v1.y * w1.y + v1.z * w1.z + v1.w * w1.w;
            }
        }
    }
    __syncthreads();
#pragma unroll
    for (int n = 0; n < NPARTS; ++n) atomicAdd(&sxp[r][n], acc[n]);
    __syncthreads();
    if (tid < 8 * NPARTS)
        sx[(size_t)(b * 8 + tid / NPARTS) * NPARTS + tid % NPARTS] =
            sxp[tid / NPARTS][tid % NPARTS] + bsel[tid % NPARTS];
}

// ============ fuse_w: Wfc -> bsw (bf16 granule-tiled, rows>=410 zero) ========
//              + G/c partials per kc quarter (shfl-reduced, deterministic)
// grid 28 = 7 rb x 4 kc
__global__ __launch_bounds__(256) void fuse_w(const float* __restrict__ Wfc,
                                              const float* __restrict__ Wexp,
                                              const float* __restrict__ bexp,
                                              u16* __restrict__ bsw,
                                              float* __restrict__ Gpart) {
    __shared__ float cmb[1024 * 12];    // 48 KB: [col][0..9]=Wexp, [10]=bexp, [11] pad

    const int tid = threadIdx.x;
    const int rb = blockIdx.x >> 2, kc = blockIdx.x & 3;

    for (int idx = tid; idx < 1024 * NPARTS; idx += 256)
        cmb[(idx / NPARTS) * 12 + (idx % NPARTS)] = Wexp[(size_t)kc * 1024 * NPARTS + idx];
    for (int idx = tid; idx < 1024; idx += 256)
        cmb[idx * 12 + 10] = bexp[kc * 1024 + idx];
    __syncthreads();

    const int c = tid & 7, rr = tid >> 3;    // rr 0..31
    float acc[2][12];
#pragma unroll
    for (int hh = 0; hh < 2; ++hh)
#pragma unroll
        for (int n = 0; n < 12; ++n) acc[hh][n] = 0.f;

    for (int j = 0; j < 16; ++j) {
        const int ktg = kc * 16 + j;
#pragma unroll
        for (int hh = 0; hh < 2; ++hh) {
            const int lr  = rr + hh * 32;
            const int row = rb * 64 + lr;
            float4 v0 = make_float4(0.f, 0.f, 0.f, 0.f);
            float4 v1 = make_float4(0.f, 0.f, 0.f, 0.f);
            if (row < NSF) {
                const float* src = Wfc + (size_t)row * KD + ktg * 64 + c * 8;
                v0 = *(const float4*)src;
                v1 = *(const float4*)(src + 4);
            }
            u16 h[8] = { f2bf(v0.x), f2bf(v0.y), f2bf(v0.z), f2bf(v0.w),
                         f2bf(v1.x), f2bf(v1.y), f2bf(v1.z), f2bf(v1.w) };
            const int g = ((lr >> 5) * 4 + (c >> 2) * 2 + ((lr >> 4) & 1)) * 64
                        + (c & 3) * 16 + (lr & 15);
            *(uint4*)&bsw[((size_t)(rb * 64 + ktg) * 512 + g) * 8] = *(uint4*)h;

            const float w[8] = { v0.x, v0.y, v0.z, v0.w, v1.x, v1.y, v1.z, v1.w };
            const int cl = j * 64 + c * 8;
#pragma unroll
            for (int jj = 0; jj < 8; ++jj) {
                const float* cb = &cmb[(cl + jj) * 12];
                float4 a0 = *(float4*)cb;
                float4 a1 = *(float4*)(cb + 4);
                float4 a2 = *(float4*)(cb + 8);
                acc[hh][0] += w[jj] * a0.x;  acc[hh][1] += w[jj] * a0.y;
                acc[hh][2] += w[jj] * a0.z;  acc[hh][3] += w[jj] * a0.w;
                acc[hh][4] += w[jj] * a1.x;  acc[hh][5] += w[jj] * a1.y;
                acc[hh][6] += w[jj] * a1.z;  acc[hh][7] += w[jj] * a1.w;
                acc[hh][8] += w[jj] * a2.x;  acc[hh][9] += w[jj] * a2.y;
                acc[hh][10] += w[jj] * a2.z;
            }
        }
    }
#pragma unroll
    for (int m = 1; m <= 4; m <<= 1)
#pragma unroll
        for (int hh = 0; hh < 2; ++hh)
#pragma unroll
            for (int n = 0; n < 11; ++n) acc[hh][n] += __shfl_xor(acc[hh][n], m);
    if (c == 0) {
#pragma unroll
        for (int hh = 0; hh < 2; ++hh) {
            const int f = rb * 64 + rr + hh * 32;
#pragma unroll
            for (int n = 0; n < 11; ++n)
                Gpart[((size_t)kc * NPAD + f) * 12 + n] = acc[hh][n];
        }
    }
}

// ============ main: A = x·Wfc^T, both operands pre-swizzled bf16 =============
// grid 448 = 7 fb x 64 tb; BK=128, dbuf; staging = pure global_load_lds (linear)
__global__ __launch_bounds__(256, 2) void main_kernel(const u16* __restrict__ xb,
                                                      const u16* __restrict__ bsw,
                                                      const float* __restrict__ Gpart,
                                                      const float* __restrict__ bfc,
                                                      const float* __restrict__ sx,
                                                      float* __restrict__ out) {
    __shared__ __align__(16) u16 As[2][8192];   // 2 x 16 KB
    __shared__ __align__(16) u16 Bs[2][8192];   // 2 x 16 KB
    __shared__ float sxs[BM][NPARTS];
    __shared__ float Gs[BN][NPARTS];
    __shared__ float cs[BN];

    const int tid = threadIdx.x;
    const int fb  = blockIdx.x >> 6;    // 0..6
    const int tb  = blockIdx.x & 63;

    const int lane = tid & 63;
    const int w  = tid >> 6;
    const int wr = w >> 1, wc = w & 1;
    const int q  = lane >> 4, ml = lane & 15;

    f32x4 acc[2][2];
#pragma unroll
    for (int mi = 0; mi < 2; ++mi)
#pragma unroll
        for (int ni = 0; ni < 2; ++ni) acc[mi][ni] = (f32x4){0.f, 0.f, 0.f, 0.f};

    const u16* abase = xb  + (size_t)tb * 64 * 4096;
    const u16* bbase = bsw + (size_t)fb * 64 * 4096;

    // epilogue staging (visible after first barrier)
    for (int idx = tid; idx < BM * NPARTS; idx += 256)
        sxs[idx / NPARTS][idx % NPARTS] = sx[(size_t)(tb * BM + idx / NPARTS) * NPARTS + idx % NPARTS];
    for (int idx = tid; idx < BN * NPARTS; idx += 256) {
        const int fl = idx / NPARTS, n = idx % NPARTS;
        const int fg = fb * BN + fl;
        Gs[fl][n] = Gpart[((size_t)0 * NPAD + fg) * 12 + n]
                  + Gpart[((size_t)1 * NPAD + fg) * 12 + n]
                  + Gpart[((size_t)2 * NPAD + fg) * 12 + n]
                  + Gpart[((size_t)3 * NPAD + fg) * 12 + n];
    }
    if (tid < BN) {
        const int fg = fb * BN + tid;
        float s = Gpart[((size_t)0 * NPAD + fg) * 12 + 10]
                + Gpart[((size_t)1 * NPAD + fg) * 12 + 10]
                + Gpart[((size_t)2 * NPAD + fg) * 12 + 10]
                + Gpart[((size_t)3 * NPAD + fg) * 12 + 10];
        cs[tid] = s + (fg < NSF ? bfc[fg] : 0.f);
    }

    // prologue: stage iteration 0 into buffer 0
#pragma unroll
    for (int k = 0; k < 4; ++k) {
        gl_lds16(abase + (k * 256 + tid) * 8, &As[0][(k * 256 + tid) * 8]);
        gl_lds16(bbase + (k * 256 + tid) * 8, &Bs[0][(k * 256 + tid) * 8]);
    }
    __syncthreads();

    int buf = 0;
#pragma unroll 2
    for (int it = 0; it < KD / BK; ++it) {
        if (it + 1 < KD / BK) {
            const size_t off = (size_t)(it + 1) * 8192;
#pragma unroll
            for (int k = 0; k < 4; ++k) {
                gl_lds16(abase + off + (k * 256 + tid) * 8, &As[buf ^ 1][(k * 256 + tid) * 8]);
                gl_lds16(bbase + off + (k * 256 + tid) * 8, &Bs[buf ^ 1][(k * 256 + tid) * 8]);
            }
        }
#pragma unroll
        for (int ks = 0; ks < 4; ++ks) {
            const int tb2 = (ks >> 1) * 512;
            const int kl  = ks & 1;
            bf16x8 av[2], bv[2];
#pragma unroll
            for (int mi = 0; mi < 2; ++mi)
                av[mi] = *(const bf16x8*)&As[buf][(tb2 + ((wr * 2 + kl) * 2 + mi) * 64 + lane) * 8];
#pragma unroll
            for (int ni = 0; ni < 2; ++ni)
                bv[ni] = *(const bf16x8*)&Bs[buf][(tb2 + ((wc * 2 + kl) * 2 + ni) * 64 + lane) * 8];
#pragma unroll
            for (int mi = 0; mi < 2; ++mi)
#pragma unroll
                for (int ni = 0; ni < 2; ++ni)
                    acc[mi][ni] = __builtin_amdgcn_mfma_f32_16x16x32_bf16(
                        av[mi], bv[ni], acc[mi][ni], 0, 0, 0);
        }
        __syncthreads();
        buf ^= 1;
    }

    // ---- epilogue: out[t, n*410+f] = A + sx[t][n]*G[f][n] + c[f] ----
#pragma unroll
    for (int ni = 0; ni < 2; ++ni) {
        const int fl = wc * 32 + ni * 16 + ml;
        const int fg = fb * BN + fl;
        if (fg >= NSF) continue;
        const float cv = cs[fl];
        float gv[NPARTS];
#pragma unroll
        for (int n = 0; n < NPARTS; ++n) gv[n] = Gs[fl][n];
#pragma unroll
        for (int mi = 0; mi < 2; ++mi) {
#pragma unroll
            for (int r = 0; r < 4; ++r) {
                const int tl = wr * 32 + mi * 16 + q * 4 + r;
                const float av = acc[mi][ni][r] + cv;
                float* orow = out + (size_t)(tb * BM + tl) * OUTF;
#pragma unroll
                for (int n = 0; n < NPARTS; ++n) {
                    int j = n * NSF + fg;
                    if (j < OUTF) orow[j] = av + sxs[tl][n] * gv[n];
                }
            }
        }
    }
}

extern "C" void kernel_launch(void* const* d_in, const int* in_sizes, int n_in,
                              void* d_out, int out_size, void* d_ws, size_t ws_size,
                              hipStream_t stream) {
    const float* x    = (const float*)d_in[0];
    const float* Wsel = (const float*)d_in[1];
    const float* bsel = (const float*)d_in[2];
    const float* Wexp = (const float*)d_in[3];
    const float* bexp = (const float*)d_in[4];
    const float* Wfc  = (const float*)d_in[5];
    const float* bfc  = (const float*)d_in[6];
    float* out = (float*)d_out;

    char* ws = (char*)d_ws;
    u16*   xb    = (u16*)  (ws + WS_XB);
    u16*   bsw   = (u16*)  (ws + WS_BSW);
    float* Gpart = (float*)(ws + WS_GP);
    float* sx    = (float*)(ws + WS_SX);

    fuse_w<<<dim3(28), dim3(256), 0, stream>>>(Wfc, Wexp, bexp, bsw, Gpart);
    fuse_x<<<dim3(512), dim3(256), 0, stream>>>(x, Wsel, bsel, xb, sx);
    main_kernel<<<dim3(7 * 64), dim3(256), 0, stream>>>(xb, bsw, Gpart, bfc, sx, out);
}